// Round 6
// baseline (14.223 us; speedup 1.0000x reference)
//
#include <hip/hip_runtime.h>

static constexpr int H = 128;
static constexpr int W = 128;
static constexpr int B = 32;
static constexpr int RPB = 4;                 // rows per block
static constexpr int WIN = RPB + 31;          // 35-row clamped window
static constexpr int GPB = H / RPB;           // 32 row-groups per batch

// Phase 1: one block per (batch, 4-row group). One 35-deep window bitmask per
// column gives all 4 heights via ctz(~(mask>>s)) -- 35 loads per 4 rows
// instead of 128. Per row: ballot threshold table (ONE __ballot(h<t) = a full
// 64-lane slice of the h[k]<h[j] matrix), then nearest-smaller left/right via
// clz/ctz. Only 2 block barriers (hmax phase, table phase; tables indexed by
// row-slot s so no cross-row races).
__global__ __launch_bounds__(W) void lr_rows(const float* __restrict__ Y,
                                             int* __restrict__ partials,
                                             int* __restrict__ out,
                                             int use_atomic) {
    const int blk = blockIdx.x;               // blk = b*GPB + rg
    const int b = blk >> 5;
    const int rg = blk & (GPB - 1);
    const int r_top = rg * RPB + (RPB - 1);   // highest row of the group
    const int j = threadIdx.x;
    const int wid = j >> 6;
    const int lane = j & 63;
    const float* __restrict__ ycol = Y + (size_t)b * H * W + j;

    // ---- window bitmask: bit k = (Y[r_top-k][j] > 0.5), rows clamped ----
    unsigned long long mask = 0ULL;
    #pragma unroll
    for (int k = 0; k < WIN; ++k) {
        int t = r_top - k; t = t < 0 ? 0 : t; // clamp: all loads in-bounds
        if (ycol[(size_t)t * W] > 0.5f) mask |= (1ULL << k);
    }
    if (r_top < WIN - 1) mask &= (2ULL << r_top) - 1ULL;  // zero t<0 bits (r_top<=31 here, shift safe)

    // ---- heights for the 4 rows: h = ctz(~(mask>>s)), serial fallback only
    //      when the run saturates the (>=32-deep) window -- ~never on this data
    int h[RPB];
    #pragma unroll
    for (int s = 0; s < RPB; ++s) {
        const int row = r_top - s;
        int hs = __builtin_ctzll(~(mask >> s));           // <= WIN-s
        if (hs == WIN - s && row - hs >= 0) {             // saturated: extend serially
            int t = row - hs;
            while (t >= 0 && ycol[(size_t)t * W] > 0.5f) { ++hs; --t; }
        }
        h[s] = hs;
    }

    __shared__ unsigned long long tbl[RPB][H + 1][2];     // [row-slot][threshold][wave]
    __shared__ int hmx[RPB][2];
    __shared__ int wmax[2];

    // ---- phase A: block max of h per row-slot ----
    #pragma unroll
    for (int s = 0; s < RPB; ++s) {
        int hm = h[s];
        #pragma unroll
        for (int off = 32; off > 0; off >>= 1)
            hm = max(hm, __shfl_xor(hm, off, 64));
        if (lane == 0) hmx[s][wid] = hm;
    }
    __syncthreads();

    // ---- phase B: threshold tables, t = 1..hmax[s] (~8-12 each) ----
    #pragma unroll
    for (int s = 0; s < RPB; ++s) {
        const int hmax = max(hmx[s][0], hmx[s][1]);       // wave-uniform
        for (int t = 1; t <= hmax; ++t) {
            const unsigned long long m = __ballot(h[s] < t);
            if (lane == 0) tbl[s][t][wid] = m;
        }
    }
    __syncthreads();

    // ---- phase C: pick my slice, nearest-smaller left/right, area ----
    int acc = 0;
    #pragma unroll
    for (int s = 0; s < RPB; ++s) {
        // h==0: tbl[s][0] is uninitialized garbage but area = 0 * (..) = 0.
        const unsigned long long mlo = tbl[s][h[s]][0];
        const unsigned long long mhi = tbl[s][h[s]][1];
        // (2ULL<<j)-1 wraps to all-ones at j==63 -> boundary falls through.
        // The j<64 branch is wave-uniform.
        int left, right;
        if (j < 64) {
            const unsigned long long below = mlo & ((1ULL << j) - 1ULL);
            const unsigned long long above = mlo & ~((2ULL << j) - 1ULL);
            left  = below ? 63 - __builtin_clzll(below) : -1;
            right = above ? __builtin_ctzll(above)
                          : (mhi ? 64 + __builtin_ctzll(mhi) : W);
        } else {
            const int jj = j - 64;
            const unsigned long long below = mhi & ((1ULL << jj) - 1ULL);
            const unsigned long long above = mhi & ~((2ULL << jj) - 1ULL);
            left  = below ? 127 - __builtin_clzll(below)
                          : (mlo ? 63 - __builtin_clzll(mlo) : -1);
            right = above ? 64 + __builtin_ctzll(above) : W;
        }
        acc = max(acc, h[s] * (right - left - 1));
    }

    // ---- block max-reduce, one plain store per block ----
    #pragma unroll
    for (int off = 32; off > 0; off >>= 1)
        acc = max(acc, __shfl_xor(acc, off, 64));
    if (lane == 0) wmax[wid] = acc;
    __syncthreads();
    if (j == 0) {
        const int m = max(wmax[0], wmax[1]);
        if (use_atomic) atomicMax(&out[b], m);            // ws-too-small fallback
        else partials[blk] = m;                           // non-atomic
    }
}

// Phase 2: out[b] = max over 32 group-partials. Plain stores fully overwrite
// out every call (no memset, no atomics, no cross-call state).
__global__ __launch_bounds__(64) void lr_reduce(const int* __restrict__ partials,
                                                int* __restrict__ out) {
    const int b = blockIdx.x;
    const int j = threadIdx.x;
    int v = (j < GPB) ? partials[b * GPB + j] : 0;        // areas are >= 0
    #pragma unroll
    for (int off = 32; off > 0; off >>= 1)
        v = max(v, __shfl_xor(v, off, 64));
    if (j == 0) out[b] = v;
}

extern "C" void kernel_launch(void* const* d_in, const int* in_sizes, int n_in,
                              void* d_out, int out_size, void* d_ws, size_t ws_size,
                              hipStream_t stream) {
    const float* Y = (const float*)d_in[0];
    int* out = (int*)d_out;

    if (ws_size >= (size_t)(B * GPB) * sizeof(int)) {     // 4 KB of partials
        int* partials = (int*)d_ws;
        lr_rows<<<B * GPB, W, 0, stream>>>(Y, partials, out, 0);
        lr_reduce<<<B, 64, 0, stream>>>(partials, out);
    } else {
        // Workspace too small: zero out, then contended-atomic fallback.
        hipMemsetAsync(out, 0, (size_t)out_size * sizeof(int), stream);
        lr_rows<<<B * GPB, W, 0, stream>>>(Y, nullptr, out, 1);
    }
}

// Round 7
// 13.180 us; speedup vs baseline: 1.0792x; 1.0792x over previous
//
#include <hip/hip_runtime.h>

static constexpr int H = 128;
static constexpr int W = 128;
static constexpr int B = 32;
static constexpr int RPB = 4;                 // rows per block
static constexpr int WIN = RPB + 31;          // 35-row clamped window
static constexpr int GPB = H / RPB;           // 32 row-groups per batch

// Kernel 1: ONE WAVE per (batch, 4-row group). Lane l owns columns l and l+64,
// so __ballot(hA<t) / __ballot(hB<t) ARE the low/high halves of the 128-column
// "strictly less" mask -- no LDS, no barriers, no bank conflicts. Each lane
// captures its own threshold slice branch-free in the t-loop (t <= wave-max h,
// ~10-12 on this data), then nearest-smaller left/right via clz/ctz.
// Heights come from a 35-deep clamped window bitmask: h = ctz(~(mask>>s)),
// with a (practically never taken) serial fallback for runs that saturate it.
__global__ __launch_bounds__(64) void lr_rows(const float* __restrict__ Y,
                                              int* __restrict__ partials,
                                              int* __restrict__ out,
                                              int use_atomic) {
    const int blk = blockIdx.x;               // blk = b*GPB + rg
    const int b = blk >> 5;
    const int rg = blk & (GPB - 1);
    const int r_top = rg * RPB + (RPB - 1);   // highest row of the group
    const int l = threadIdx.x;                // single wave: lane == threadIdx
    const float* __restrict__ yA = Y + (size_t)b * H * W + l;       // col l
    const float* __restrict__ yB = yA + 64;                         // col l+64

    // ---- window bitmasks: bit k = (Y[r_top-k][col] > 0.5), rows clamped ----
    unsigned long long mA = 0ULL, mB = 0ULL;
    #pragma unroll
    for (int k = 0; k < WIN; ++k) {
        int t = r_top - k; t = t < 0 ? 0 : t; // clamp: all loads in-bounds
        if (yA[(size_t)t * W] > 0.5f) mA |= (1ULL << k);
        if (yB[(size_t)t * W] > 0.5f) mB |= (1ULL << k);
    }
    if (r_top < WIN - 1) {                    // zero the clamped duplicate bits
        const unsigned long long keep = (2ULL << r_top) - 1ULL;  // r_top<=33: safe
        mA &= keep; mB &= keep;
    }

    // ---- heights for the RPB rows (s = offset below r_top) ----
    int hA[RPB], hB[RPB];
    #pragma unroll
    for (int s = 0; s < RPB; ++s) {
        const int r = r_top - s;
        int a = __builtin_ctzll(~(mA >> s));  // run length, <= WIN-s
        if (a == WIN - s && r - a >= 0) {     // saturated: extend serially (rare)
            int t = r - a;
            while (t >= 0 && yA[(size_t)t * W] > 0.5f) { ++a; --t; }
        }
        int c = __builtin_ctzll(~(mB >> s));
        if (c == WIN - s && r - c >= 0) {
            int t = r - c;
            while (t >= 0 && yB[(size_t)t * W] > 0.5f) { ++c; --t; }
        }
        hA[s] = a; hB[s] = c;
    }

    // ---- wave max of all heights -> shared ballot loop bound ----
    int hm = 0;
    #pragma unroll
    for (int s = 0; s < RPB; ++s) hm = max(hm, max(hA[s], hB[s]));
    #pragma unroll
    for (int off = 32; off > 0; off >>= 1)
        hm = max(hm, __shfl_xor(hm, off, 64));

    // ---- ballot + branch-free capture: per row s, lane's own mask slice ----
    // loX/hiX stay registers: indices are compile-time after unroll (rule #20).
    unsigned long long loA[RPB] = {}, hiA[RPB] = {};
    unsigned long long loB[RPB] = {}, hiB[RPB] = {};
    for (int t = 1; t <= hm; ++t) {           // hm==0: skipped, all areas 0
        #pragma unroll
        for (int s = 0; s < RPB; ++s) {
            const unsigned long long lo = __ballot(hA[s] < t);  // cols 0..63
            const unsigned long long hi = __ballot(hB[s] < t);  // cols 64..127
            if (hA[s] == t) { loA[s] = lo; hiA[s] = hi; }       // cndmask pairs
            if (hB[s] == t) { loB[s] = lo; hiB[s] = hi; }
        }
    }
    // h==0 lanes never capture (t starts at 1): masks stay 0 -> area = 0. OK.

    // ---- nearest-smaller left/right per owned column, area, accumulate ----
    int acc = 0;
    #pragma unroll
    for (int s = 0; s < RPB; ++s) {
        {   // column l (low half). (2ULL<<63) wraps to 0 -> right edge OK.
            const unsigned long long below = loA[s] & ((1ULL << l) - 1ULL);
            const unsigned long long above = loA[s] & ~((2ULL << l) - 1ULL);
            const int left  = below ? 63 - __builtin_clzll(below) : -1;
            const int right = above ? __builtin_ctzll(above)
                                    : (hiA[s] ? 64 + __builtin_ctzll(hiA[s]) : W);
            acc = max(acc, hA[s] * (right - left - 1));
        }
        {   // column l+64 (high half)
            const unsigned long long below = hiB[s] & ((1ULL << l) - 1ULL);
            const unsigned long long above = hiB[s] & ~((2ULL << l) - 1ULL);
            const int left  = below ? 64 + 63 - __builtin_clzll(below)
                                    : (loB[s] ? 63 - __builtin_clzll(loB[s]) : -1);
            const int right = above ? 64 + __builtin_ctzll(above) : W;
            acc = max(acc, hB[s] * (right - left - 1));
        }
    }

    // ---- wave max-reduce, one plain store per block ----
    #pragma unroll
    for (int off = 32; off > 0; off >>= 1)
        acc = max(acc, __shfl_xor(acc, off, 64));
    if (l == 0) {
        if (use_atomic) atomicMax(&out[b], acc);   // ws-too-small fallback only
        else partials[blk] = acc;                  // non-atomic
    }
}

// Kernel 2: out[b] = max over 32 group-partials. Plain stores fully overwrite
// out every call (no memset, no atomics, no cross-call state).
__global__ __launch_bounds__(64) void lr_reduce(const int* __restrict__ partials,
                                                int* __restrict__ out) {
    const int b = blockIdx.x;
    const int j = threadIdx.x;
    int v = (j < GPB) ? partials[b * GPB + j] : 0;   // areas are >= 0
    #pragma unroll
    for (int off = 32; off > 0; off >>= 1)
        v = max(v, __shfl_xor(v, off, 64));
    if (j == 0) out[b] = v;
}

extern "C" void kernel_launch(void* const* d_in, const int* in_sizes, int n_in,
                              void* d_out, int out_size, void* d_ws, size_t ws_size,
                              hipStream_t stream) {
    const float* Y = (const float*)d_in[0];
    int* out = (int*)d_out;

    if (ws_size >= (size_t)(B * GPB) * sizeof(int)) {    // 4 KB of partials
        int* partials = (int*)d_ws;
        lr_rows<<<B * GPB, 64, 0, stream>>>(Y, partials, out, 0);
        lr_reduce<<<B, 64, 0, stream>>>(partials, out);
    } else {
        // Workspace too small: zero out, then contended-atomic fallback.
        hipMemsetAsync(out, 0, (size_t)out_size * sizeof(int), stream);
        lr_rows<<<B * GPB, 64, 0, stream>>>(Y, nullptr, out, 1);
    }
}